// Round 1
// baseline (17361.620 us; speedup 1.0000x reference)
//
#include <hip/hip_runtime.h>
#include <hip/hip_fp16.h>

typedef unsigned short u16;
typedef unsigned int u32;
typedef unsigned long long u64;

#define NT 512      // time steps
#define NB 256      // batch
#define NH 1024     // hidden
#define NE 128      // emb dim
#define NHE 1152    // H+E
#define NL 17       // labels
#define MT 4        // batch tiles (64 rows each)
#define JTILES 32   // hidden-col tiles (32 cols each)
#define XKC 36      // K-chunks (32 wide) for x part
#define HKC 32      // K-chunks for h part
#define KCT 68      // XKC + HKC
#define NBLK 128    // MT * JTILES
#define THREADS 256

typedef __attribute__((ext_vector_type(8))) _Float16 half8;
typedef __attribute__((ext_vector_type(4))) float f32x4;

// ---- workspace layout (bytes) ----
#define WS_CNT     0ull
#define WS_HBUF    4096ull                   // 2 * 4 * 32 * 4096 = 1,048,576
#define WS_WPACK   1052672ull                // 32*68*6*1024     = 13,369,344
#define WS_WOPACK  14422016ull               // 32*2*1024        = 65,536
#define WS_XPACK   14487552ull               // 4*512*36*4096    = 301,989,888
#define WS_TOTAL   316477440ull

__device__ __forceinline__ u16 f2h(float f) {
  __half h = __float2half(f);
  return __builtin_bit_cast(u16, h);
}
__device__ __forceinline__ float h2f(u16 u) {
  return __half2float(__builtin_bit_cast(__half, u));
}
__device__ __forceinline__ uint4 pack8h(const u16* o) {
  uint4 v;
  v.x = (u32)o[0] | ((u32)o[1] << 16);
  v.y = (u32)o[2] | ((u32)o[3] << 16);
  v.z = (u32)o[4] | ((u32)o[5] << 16);
  v.w = (u32)o[6] | ((u32)o[7] << 16);
  return v;
}

// ---------------- zero counters + h parity-0 ----------------
__global__ void zero_ws(uint4* p) {
  // zero [0 .. 4096 + 524288) bytes = 33024 uint4
  int idx = blockIdx.x * 256 + threadIdx.x;
  if (idx < 33024) {
    uint4 z; z.x = 0; z.y = 0; z.z = 0; z.w = 0;
    p[idx] = z;
  }
}

// ---------------- pack weights into B-fragment order ----------------
// wpack unit layout: (((jt*68+kc)*3+g)*2+ni)*64 + lane  (16B each)
// frag: lane l -> col = (l&15), k = (l>>4)*8 + e   (within 32-wide k chunk)
__global__ void pack_w(const float* __restrict__ Wih, const float* __restrict__ Whh,
                       const float* __restrict__ Wout, u16* __restrict__ wpack,
                       u16* __restrict__ wopack) {
  int idx = blockIdx.x * 256 + threadIdx.x;
  const int WUNITS = JTILES * KCT * 3 * 2 * 64;   // 835584
  if (idx < WUNITS) {
    int l = idx & 63;
    int r = idx >> 6;
    int ni = r & 1; r >>= 1;
    int g = r % 3;  r /= 3;
    int kc = r % KCT; r /= KCT;
    int jt = r;
    int row = g * NH + jt * 32 + ni * 16 + (l & 15);
    int kk = (l >> 4) * 8;
    const float* src = (kc < XKC) ? (Wih + (size_t)row * NHE + kc * 32 + kk)
                                  : (Whh + (size_t)row * NH + (kc - XKC) * 32 + kk);
    u16 o[8];
#pragma unroll
    for (int e = 0; e < 8; ++e) o[e] = f2h(src[e]);
    ((uint4*)wpack)[idx] = pack8h(o);
  } else if (idx < WUNITS + HKC * 2 * 64) {
    int j = idx - WUNITS;
    int l = j & 63; j >>= 6;
    int ni = j & 1; int kc = j >> 1;
    int col = (l & 15) + 16 * ni;
    int kk = kc * 32 + (l >> 4) * 8;
    u16 o[8];
#pragma unroll
    for (int e = 0; e < 8; ++e)
      o[e] = (col < NL) ? f2h(Wout[(size_t)col * NH + kk + e]) : (u16)0;
    ((uint4*)wopack)[idx - WUNITS] = pack8h(o);
  }
}

// ---------------- pack x = [seg | emb(prev_label)] into A-fragment order ----------------
// xpack unit layout per (m,t): (kc*4 + sub)*64 + lane ; row = sub*16+(l&15), k = kc*32+(l>>4)*8+e
__global__ void pack_x(const float* __restrict__ seg, const int* __restrict__ labels,
                       const float* __restrict__ emb, u16* __restrict__ xpack) {
  __shared__ float ls[64][33];
  __shared__ int lbl[64];
  const int bid = blockIdx.x;
  const int t = bid & (NT - 1);
  const int m = bid >> 9;
  const int tid = threadIdx.x;
  u16* outb = xpack + (size_t)(m * NT + t) * (XKC * 4 * 64 * 8);
  const int r = tid >> 2, qq = tid & 3;
  const int sub = tid >> 6, l = tid & 63;
  const int row = sub * 16 + (l & 15), c0 = (l >> 4) * 8;

  for (int kc = 0; kc < 32; ++kc) {
    const float* s = seg + ((size_t)(m * 64 + r) * NT + t) * NH + kc * 32 + qq * 8;
    float4 a = ((const float4*)s)[0];
    float4 b2 = ((const float4*)s)[1];
    ls[r][qq * 8 + 0] = a.x;  ls[r][qq * 8 + 1] = a.y;
    ls[r][qq * 8 + 2] = a.z;  ls[r][qq * 8 + 3] = a.w;
    ls[r][qq * 8 + 4] = b2.x; ls[r][qq * 8 + 5] = b2.y;
    ls[r][qq * 8 + 6] = b2.z; ls[r][qq * 8 + 7] = b2.w;
    __syncthreads();
    u16 o[8];
#pragma unroll
    for (int e = 0; e < 8; ++e) o[e] = f2h(ls[row][c0 + e]);
    ((uint4*)outb)[(kc * 4 + sub) * 64 + l] = pack8h(o);
    __syncthreads();
  }
  if (tid < 64)
    lbl[tid] = (t == 0) ? NL : labels[(size_t)(m * 64 + tid) * NT + (t - 1)];
  __syncthreads();
  for (int u = tid; u < 1024; u += 256) {
    int ll = u & 63; int sb = (u >> 6) & 3; int kc = 32 + (u >> 8);
    int rw = sb * 16 + (ll & 15);
    int kk = (kc - 32) * 32 + ((ll >> 4) * 8);
    const float* s = emb + (size_t)lbl[rw] * NE + kk;
    float4 a = ((const float4*)s)[0];
    float4 b2 = ((const float4*)s)[1];
    u16 o[8];
    o[0] = f2h(a.x); o[1] = f2h(a.y); o[2] = f2h(a.z); o[3] = f2h(a.w);
    o[4] = f2h(b2.x); o[5] = f2h(b2.y); o[6] = f2h(b2.z); o[7] = f2h(b2.w);
    ((uint4*)outb)[(kc * 4 + sb) * 64 + ll] = pack8h(o);
  }
}

// ---------------- persistent GRU kernel ----------------
#define MFMA16(a, b, c) __builtin_amdgcn_mfma_f32_16x16x32_f16((a), (b), (c), 0, 0, 0)

#define LOADX(i, BA, BB) do { \
  const int kc_ = w * 9 + (i); \
  const size_t xu_ = xbase_u + (size_t)(kc_ * 4) * 64 + l; \
  BA[0] = xp[xu_]; BA[1] = xp[xu_ + 64]; BA[2] = xp[xu_ + 128]; BA[3] = xp[xu_ + 192]; \
  const size_t wu_ = wbase_u + (size_t)(kc_ * 6) * 64 + l; \
  BB[0] = wp[wu_];       BB[1] = wp[wu_ + 64]; \
  BB[2] = wp[wu_ + 128]; BB[3] = wp[wu_ + 192]; \
  BB[4] = wp[wu_ + 256]; BB[5] = wp[wu_ + 320]; \
} while (0)

#define MFMAX(BA, BB) do { \
  _Pragma("unroll") \
  for (int s_ = 0; s_ < 4; ++s_) { \
    half8 a_ = __builtin_bit_cast(half8, BA[s_]); \
    _Pragma("unroll") \
    for (int n_ = 0; n_ < 2; ++n_) { \
      aR[s_][n_]  = MFMA16(a_, __builtin_bit_cast(half8, BB[n_]),     aR[s_][n_]); \
      aZ[s_][n_]  = MFMA16(a_, __builtin_bit_cast(half8, BB[2 + n_]), aZ[s_][n_]); \
      aXN[s_][n_] = MFMA16(a_, __builtin_bit_cast(half8, BB[4 + n_]), aXN[s_][n_]); \
    } \
  } \
} while (0)

#define LOADHB(i, BB, BO) do { \
  const int kc_ = XKC + w * 8 + (i); \
  const size_t wu_ = wbase_u + (size_t)(kc_ * 6) * 64 + l; \
  BB[0] = wp[wu_];       BB[1] = wp[wu_ + 64]; \
  BB[2] = wp[wu_ + 128]; BB[3] = wp[wu_ + 192]; \
  BB[4] = wp[wu_ + 256]; BB[5] = wp[wu_ + 320]; \
  if (duty) { \
    const size_t ou_ = (size_t)((w * 8 + (i)) * 2) * 64 + l; \
    BO[0] = wo[ou_]; BO[1] = wo[ou_ + 64]; \
  } \
} while (0)

#define MFMAH(ci, BB, BO) do { \
  _Pragma("unroll") \
  for (int s_ = 0; s_ < 4; ++s_) { \
    uint4 av_; \
    av_.x = (u32)hA[ci][s_][0]; av_.y = (u32)(hA[ci][s_][0] >> 32); \
    av_.z = (u32)hA[ci][s_][1]; av_.w = (u32)(hA[ci][s_][1] >> 32); \
    half8 a_ = __builtin_bit_cast(half8, av_); \
    _Pragma("unroll") \
    for (int n_ = 0; n_ < 2; ++n_) { \
      aR[s_][n_]  = MFMA16(a_, __builtin_bit_cast(half8, BB[n_]),     aR[s_][n_]); \
      aZ[s_][n_]  = MFMA16(a_, __builtin_bit_cast(half8, BB[2 + n_]), aZ[s_][n_]); \
      aHN[s_][n_] = MFMA16(a_, __builtin_bit_cast(half8, BB[4 + n_]), aHN[s_][n_]); \
    } \
  } \
  if (duty) { \
    _Pragma("unroll") \
    for (int s_ = 0; s_ < 4; ++s_) { \
      uint4 av_; \
      av_.x = (u32)hA[ci][s_][0]; av_.y = (u32)(hA[ci][s_][0] >> 32); \
      av_.z = (u32)hA[ci][s_][1]; av_.w = (u32)(hA[ci][s_][1] >> 32); \
      half8 a_ = __builtin_bit_cast(half8, av_); \
      aL[s_][0] = MFMA16(a_, __builtin_bit_cast(half8, BO[0]), aL[s_][0]); \
      aL[s_][1] = MFMA16(a_, __builtin_bit_cast(half8, BO[1]), aL[s_][1]); \
    } \
  } \
} while (0)

#define WRSLICE(gi, ACC) do { \
  u16 o_[8]; \
  _Pragma("unroll") for (int n_ = 0; n_ < 2; ++n_) \
  _Pragma("unroll") for (int r_ = 0; r_ < 4; ++r_) o_[n_ * 4 + r_] = f2h(ACC[tw][n_][r_]); \
  redbuf[((tw * 3 + slot) * 4 + (gi)) * 64 + l] = pack8h(o_); \
} while (0)

#define RDSLICE(gi, SACC) do { \
  uint4 v_ = redbuf[((w * 3 + slot) * 4 + (gi)) * 64 + l]; \
  u32 vv_[4] = {v_.x, v_.y, v_.z, v_.w}; \
  _Pragma("unroll") for (int n_ = 0; n_ < 2; ++n_) \
  _Pragma("unroll") for (int r_ = 0; r_ < 4; ++r_) { \
    const int ix_ = n_ * 4 + r_; \
    u16 hu_ = (u16)(vv_[ix_ >> 1] >> ((ix_ & 1) * 16)); \
    SACC[n_][r_] += h2f(hu_); \
  } \
} while (0)

__global__ __launch_bounds__(THREADS, 1)
void gru_persist(const u16* __restrict__ xpack, const u16* __restrict__ wpack,
                 const u16* __restrict__ wopack,
                 const float* __restrict__ bih, const float* __restrict__ bhh,
                 const float* __restrict__ bout,
                 u64* __restrict__ hbuf, u32* __restrict__ counters,
                 float* __restrict__ out) {
  __shared__ uint4 redbuf[4 * 3 * 4 * 64];   // 48KB: f16 gate exchange / f32 logits exchange
  __shared__ u16 hbf[64 * 40];               // 5KB fp16 bounce for h fragment write

  const int bid = blockIdx.x;
  const int xcd = bid & 7;
  const int q = bid >> 3;
  const int m = q & 3;
  const int jslot = q >> 2;
  const int jt = jslot * 8 + xcd;            // 0..31, same-jt blocks co-located per XCD
  const bool duty = (jt == 0);
  const int tid = threadIdx.x;
  const int w = tid >> 6, l = tid & 63;
  const int l15 = l & 15, l4 = l >> 4;

  const uint4* xp = (const uint4*)xpack;
  const uint4* wp = (const uint4*)wpack;
  const uint4* wo = (const uint4*)wopack;
  f32x4* redv = (f32x4*)redbuf;
  u32* cnt = counters + m * 16;
  const size_t wbase_u = (size_t)jt * (KCT * 6 * 64);

  // biases (zero in this problem, honored anyway)
  float br[2], bz[2], bxn[2], bhn[2];
#pragma unroll
  for (int ni = 0; ni < 2; ++ni) {
    int col = jt * 32 + ni * 16 + l15;
    br[ni] = bih[col] + bhh[col];
    bz[ni] = bih[NH + col] + bhh[NH + col];
    bxn[ni] = bih[2 * NH + col];
    bhn[ni] = bhh[2 * NH + col];
  }
  float hold[2][4] = {{0.f, 0.f, 0.f, 0.f}, {0.f, 0.f, 0.f, 0.f}};
  const f32x4 z4 = {0.f, 0.f, 0.f, 0.f};

  for (int t = 0; t < NT; ++t) {
    const int par = t & 1;
    const size_t xbase_u = (size_t)(m * NT + t) * (XKC * 4 * 64);
    f32x4 aR[4][2], aZ[4][2], aXN[4][2], aHN[4][2], aL[4][2];
#pragma unroll
    for (int s_ = 0; s_ < 4; ++s_)
#pragma unroll
      for (int n_ = 0; n_ < 2; ++n_) {
        aR[s_][n_] = z4; aZ[s_][n_] = z4; aXN[s_][n_] = z4;
        aHN[s_][n_] = z4; aL[s_][n_] = z4;
      }

    // ---- x phase (no cross-block dependency): 9 chunks per wave ----
    {
      uint4 xA0[4], xA1[4], xB0[6], xB1[6];
      LOADX(0, xA0, xB0);
#pragma unroll
      for (int i = 0; i < 9; ++i) {
        if ((i & 1) == 0) { if (i < 8) LOADX(i + 1, xA1, xB1); MFMAX(xA0, xB0); }
        else              { if (i < 8) LOADX(i + 1, xA0, xB0); MFMAX(xA1, xB1); }
      }
    }

    // ---- wait for group's h(t) ----
    if (tid == 0) {
      const u32 target = 32u * (u32)t;
      while (__hip_atomic_load(cnt, __ATOMIC_RELAXED, __HIP_MEMORY_SCOPE_AGENT) < target)
        __builtin_amdgcn_s_sleep(2);
    }
    __syncthreads();

    // ---- h phase: preload all A-frags (LLC-coherent), stream B with double buffer ----
    u64 hA[8][4][2];
    {
      u64* hb_ = hbuf + (size_t)(par * MT + m) * (HKC * 4 * 64 * 2);
#pragma unroll
      for (int c_ = 0; c_ < 8; ++c_)
#pragma unroll
        for (int s_ = 0; s_ < 4; ++s_) {
          const size_t o_ = ((size_t)((w * 8 + c_) * 4 + s_) * 64 + l) * 2;
          hA[c_][s_][0] = __hip_atomic_load(hb_ + o_, __ATOMIC_RELAXED, __HIP_MEMORY_SCOPE_AGENT);
          hA[c_][s_][1] = __hip_atomic_load(hb_ + o_ + 1, __ATOMIC_RELAXED, __HIP_MEMORY_SCOPE_AGENT);
        }
    }
    {
      uint4 hB0[6], hB1[6], hO0[2], hO1[2];
      LOADHB(0, hB0, hO0);
#pragma unroll
      for (int i = 0; i < 8; ++i) {
        if ((i & 1) == 0) { if (i < 7) LOADHB(i + 1, hB1, hO1); MFMAH(i, hB0, hO0); }
        else              { if (i < 7) LOADHB(i + 1, hB0, hO0); MFMAH(i, hB1, hO1); }
      }
    }

    // ---- cross-wave k-reduction (f16 exchange), wave w owns row subtile w ----
    f32x4 sR[2], sZ[2], sXN[2], sHN[2];
#pragma unroll
    for (int tw = 0; tw < 4; ++tw) {
      if (tw == w) {
        sR[0] = aR[tw][0]; sR[1] = aR[tw][1];
        sZ[0] = aZ[tw][0]; sZ[1] = aZ[tw][1];
        sXN[0] = aXN[tw][0]; sXN[1] = aXN[tw][1];
        sHN[0] = aHN[tw][0]; sHN[1] = aHN[tw][1];
      } else {
        const int slot = (w > tw) ? (w - 1) : w;
        WRSLICE(0, aR); WRSLICE(1, aZ); WRSLICE(2, aXN); WRSLICE(3, aHN);
      }
    }
    __syncthreads();
#pragma unroll
    for (int slot = 0; slot < 3; ++slot) {
      RDSLICE(0, sR); RDSLICE(1, sZ); RDSLICE(2, sXN); RDSLICE(3, sHN);
    }

    // ---- gate math (fp32 carried state in registers) ----
#pragma unroll
    for (int ni = 0; ni < 2; ++ni) {
      const int col = l15 + 16 * ni;
#pragma unroll
      for (int rg = 0; rg < 4; ++rg) {
        float R = sR[ni][rg] + br[ni];
        float Z = sZ[ni][rg] + bz[ni];
        float XNv = sXN[ni][rg] + bxn[ni];
        float HNv = sHN[ni][rg] + bhn[ni];
        float r_ = 1.f / (1.f + __expf(-R));
        float z_ = 1.f / (1.f + __expf(-Z));
        float pre = XNv + r_ * HNv;
        float e2 = __expf(2.f * pre);
        float n_ = 1.f - 2.f / (e2 + 1.f);
        float hn_ = (1.f - z_) * n_ + z_ * hold[ni][rg];
        hold[ni][rg] = hn_;
        const int row = w * 16 + l4 * 4 + rg;
        hbf[row * 40 + col] = f2h(hn_);
      }
    }
    __syncthreads();

    // ---- write h(t+1) fragment chunk (kc = jt) to global, LLC-coherent ----
    {
      const int row = w * 16 + l15;
      const uint4 hv = *(const uint4*)&hbf[(size_t)row * 40 + l4 * 8];
      u64 lo = ((u64)hv.y << 32) | (u64)hv.x;
      u64 hi = ((u64)hv.w << 32) | (u64)hv.z;
      u64* dst = hbuf + (size_t)((par ^ 1) * MT + m) * (HKC * 4 * 64 * 2)
                      + ((size_t)(jt * 4 + w) * 64 + l) * 2;
      __hip_atomic_store(dst, lo, __ATOMIC_RELAXED, __HIP_MEMORY_SCOPE_AGENT);
      __hip_atomic_store(dst + 1, hi, __ATOMIC_RELAXED, __HIP_MEMORY_SCOPE_AGENT);
    }
    __syncthreads();   // drains all vm stores before flag
    if (tid == 0)
      __hip_atomic_fetch_add(cnt, 1u, __ATOMIC_RELAXED, __HIP_MEMORY_SCOPE_AGENT);

    // ---- duty blocks: logits[:, t-1] from this step's h A-frags (rides in slack) ----
    if (duty && t > 0) {
      f32x4 sL[2];
#pragma unroll
      for (int tw = 0; tw < 4; ++tw) {
        if (tw == w) { sL[0] = aL[tw][0]; sL[1] = aL[tw][1]; }
        else {
          const int slot = (w > tw) ? (w - 1) : w;
          redv[((tw * 3 + slot) * 2 + 0) * 64 + l] = aL[tw][0];
          redv[((tw * 3 + slot) * 2 + 1) * 64 + l] = aL[tw][1];
        }
      }
      __syncthreads();
#pragma unroll
      for (int slot = 0; slot < 3; ++slot) {
        sL[0] += redv[((w * 3 + slot) * 2 + 0) * 64 + l];
        sL[1] += redv[((w * 3 + slot) * 2 + 1) * 64 + l];
      }
#pragma unroll
      for (int ni = 0; ni < 2; ++ni) {
        const int col = l15 + 16 * ni;
        if (col < NL) {
#pragma unroll
          for (int rg = 0; rg < 4; ++rg) {
            const int row = w * 16 + l4 * 4 + rg;
            const size_t b_ = (size_t)m * 64 + row;
            out[(b_ * NT + (t - 1)) * NL + col] = sL[ni][rg] + bout[col];
          }
        }
      }
      __syncthreads();
    }
  }

  // ---- epilogue: logits[:, 511] from h_512 (parity 0) ----
  if (duty) {
    if (tid == 0) {
      while (__hip_atomic_load(cnt, __ATOMIC_RELAXED, __HIP_MEMORY_SCOPE_AGENT) < 32u * 512u)
        __builtin_amdgcn_s_sleep(2);
    }
    __syncthreads();
    f32x4 aL2[4][2];
#pragma unroll
    for (int s_ = 0; s_ < 4; ++s_) { aL2[s_][0] = z4; aL2[s_][1] = z4; }
    u64* hb_ = hbuf + (size_t)(0 * MT + m) * (HKC * 4 * 64 * 2);
#pragma unroll
    for (int c_ = 0; c_ < 8; ++c_) {
      uint4 o0 = wo[(size_t)((w * 8 + c_) * 2 + 0) * 64 + l];
      uint4 o1 = wo[(size_t)((w * 8 + c_) * 2 + 1) * 64 + l];
#pragma unroll
      for (int s_ = 0; s_ < 4; ++s_) {
        const size_t off_ = ((size_t)((w * 8 + c_) * 4 + s_) * 64 + l) * 2;
        u64 v0 = __hip_atomic_load(hb_ + off_, __ATOMIC_RELAXED, __HIP_MEMORY_SCOPE_AGENT);
        u64 v1 = __hip_atomic_load(hb_ + off_ + 1, __ATOMIC_RELAXED, __HIP_MEMORY_SCOPE_AGENT);
        uint4 av_;
        av_.x = (u32)v0; av_.y = (u32)(v0 >> 32); av_.z = (u32)v1; av_.w = (u32)(v1 >> 32);
        half8 a_ = __builtin_bit_cast(half8, av_);
        aL2[s_][0] = MFMA16(a_, __builtin_bit_cast(half8, o0), aL2[s_][0]);
        aL2[s_][1] = MFMA16(a_, __builtin_bit_cast(half8, o1), aL2[s_][1]);
      }
    }
    f32x4 sL[2];
#pragma unroll
    for (int tw = 0; tw < 4; ++tw) {
      if (tw == w) { sL[0] = aL2[tw][0]; sL[1] = aL2[tw][1]; }
      else {
        const int slot = (w > tw) ? (w - 1) : w;
        redv[((tw * 3 + slot) * 2 + 0) * 64 + l] = aL2[tw][0];
        redv[((tw * 3 + slot) * 2 + 1) * 64 + l] = aL2[tw][1];
      }
    }
    __syncthreads();
#pragma unroll
    for (int slot = 0; slot < 3; ++slot) {
      sL[0] += redv[((w * 3 + slot) * 2 + 0) * 64 + l];
      sL[1] += redv[((w * 3 + slot) * 2 + 1) * 64 + l];
    }
#pragma unroll
    for (int ni = 0; ni < 2; ++ni) {
      const int col = l15 + 16 * ni;
      if (col < NL) {
#pragma unroll
        for (int rg = 0; rg < 4; ++rg) {
          const int row = w * 16 + l4 * 4 + rg;
          const size_t b_ = (size_t)m * 64 + row;
          out[(b_ * NT + 511) * NL + col] = sL[ni][rg] + bout[col];
        }
      }
    }
  }
}

extern "C" void kernel_launch(void* const* d_in, const int* in_sizes, int n_in,
                              void* d_out, int out_size, void* d_ws, size_t ws_size,
                              hipStream_t stream) {
  (void)in_sizes; (void)n_in; (void)out_size;
  const float* seg   = (const float*)d_in[0];
  const int*   labels= (const int*)d_in[1];
  const float* emb   = (const float*)d_in[2];
  const float* Wih   = (const float*)d_in[3];
  const float* Whh   = (const float*)d_in[4];
  const float* bih   = (const float*)d_in[5];
  const float* bhh   = (const float*)d_in[6];
  const float* Wout  = (const float*)d_in[7];
  const float* bout  = (const float*)d_in[8];
  float* out = (float*)d_out;
  char* ws = (char*)d_ws;
  if (ws_size < WS_TOTAL) return;  // fail loudly rather than corrupt memory

  zero_ws<<<129, 256, 0, stream>>>((uint4*)(ws + WS_CNT));
  pack_w<<<3280, 256, 0, stream>>>(Wih, Whh, Wout,
                                   (u16*)(ws + WS_WPACK), (u16*)(ws + WS_WOPACK));
  pack_x<<<2048, 256, 0, stream>>>(seg, labels, emb, (u16*)(ws + WS_XPACK));
  gru_persist<<<NBLK, THREADS, 0, stream>>>(
      (const u16*)(ws + WS_XPACK), (const u16*)(ws + WS_WPACK),
      (const u16*)(ws + WS_WOPACK), bih, bhh, bout,
      (u64*)(ws + WS_HBUF), (u32*)(ws + WS_CNT), out);
}